// Round 7
// baseline (762.645 us; speedup 1.0000x reference)
//
#include <hip/hip_runtime.h>
#include <math.h>

#define B_ 128
#define NTOK 577
#define P_ 576
#define D_ 768
#define G_ 17
#define KOCC 10
#define INV_TEMP 10.0f
#define U17 (1.0f / 17.0f)
#define NCHUNK 9

// ws layout (float offsets):
#define OFF_SIM 0                               // [B][576]
#define OFF_GFP (OFF_SIM + B_ * P_)             // [NCHUNK][B][17][768]
#define GFP_PART ((size_t)B_ * G_ * D_)

// KZ: atomic-fallback only — zero feats group rows before k13's atomicAdds.
__global__ __launch_bounds__(256) void kz_zero(float* __restrict__ feats) {
    int b = blockIdx.x;
    float4 z = {0.f, 0.f, 0.f, 0.f};
    float4* fb = (float4*)(feats + ((size_t)b * 18 + 1) * D_);
    for (int i = threadIdx.x; i < G_ * D_ / 4; i += 256) fb[i] = z;
}

// K13 v7: fused scores + softmax + PV. grid (NCHUNK, B_), block 512 (8 waves).
// TLP push vs r6 (which was latency-bound at 2 blocks/CU from 60KB LDS,
// occupancy 31%): w staged in TWO 26KB halves ([17][384]) with a mid-loop
// restage -> LDS 26.1KB -> wave-slot-limited 4 blocks/CU (32 waves/CU),
// 2x r6's TLP. VGPR kept <=64 (the 8-waves/SIMD boundary): no cls prefetch
// regs (cls read in-loop, L1-hot), atile aliases wbuf (barrier-guarded).
// k0 is GONE: gw transpose folded into staging (gw is 52KB L2-resident),
// |cls|^2 folded in as accumulator row s19 (reduced by the same shuffles),
// cls->feats copy moved to k24.
__global__ __launch_bounds__(512) void k13_score_pv(const float* __restrict__ x,
                                                    const float* __restrict__ gw,
                                                    float* __restrict__ sim,
                                                    float* __restrict__ attn,
                                                    float* __restrict__ gfp,
                                                    float* __restrict__ feats,
                                                    int use_part) {
    __shared__ __align__(16) float wbuf[G_ * 384];   // 26112 B
    float* atile = wbuf;                             // [20*68] alias, post-loop only

    int tid = threadIdx.x;
    int b = blockIdx.y, chunk = blockIdx.x;
    const float* clsrow = x + (size_t)b * NTOK * D_;

    int lane = tid & 63, wave = tid >> 6;
    int lr = lane & 15, rh = lane >> 4;
    int lr4 = lr * 4;
    int pbase = wave * 8 + rh * 2;                   // 2 p-rows per thread
    const float* xp0 = x + ((size_t)(b * NTOK + 1 + chunk * 64 + pbase)) * D_ + lr4;

    // first x prefetch before staging (independent of LDS)
    float4 xv[2], xn[2];
    xv[0] = *(const float4*)(xp0);
    xv[1] = *(const float4*)(xp0 + D_);
    xn[0] = xv[0]; xn[1] = xv[1];

    // stage w half 0 (transposed read from gw: d-major -> [g][d])
    for (int i = tid; i < G_ * 96; i += 512) {
        int g = i / 96, dq = i - g * 96;
        const float* gp = gw + (size_t)(dq * 4) * G_ + g;
        float4 w;
        w.x = gp[0]; w.y = gp[G_]; w.z = gp[2 * G_]; w.w = gp[3 * G_];
        *(float4*)&wbuf[g * 384 + dq * 4] = w;
    }

    float s[19][2];
    #pragma unroll
    for (int i = 0; i < 19; ++i) { s[i][0] = 0.f; s[i][1] = 0.f; }
    float s19 = 0.f;                                 // |cls|^2 partial

    __syncthreads();   // half 0 ready

    for (int half = 0; half < 2; ++half) {
        if (half) {
            __syncthreads();   // all waves done with half 0
            for (int i = tid; i < G_ * 96; i += 512) {
                int g = i / 96, dq = i - g * 96;
                const float* gp = gw + (size_t)(384 + dq * 4) * G_ + g;
                float4 w;
                w.x = gp[0]; w.y = gp[G_]; w.z = gp[2 * G_]; w.w = gp[3 * G_];
                *(float4*)&wbuf[g * 384 + dq * 4] = w;
            }
            __syncthreads();   // half 1 ready
        }
        #pragma unroll
        for (int kc2 = 0; kc2 < 6; ++kc2) {
            int kc = half * 6 + kc2;
            if (kc < 11) {
                xn[0] = *(const float4*)(xp0 + (kc + 1) * 64);
                xn[1] = *(const float4*)(xp0 + (kc + 1) * 64 + D_);
            }
            float4 cls4 = *(const float4*)(clsrow + kc * 64 + lr4);  // L1-hot
            const float* wk = wbuf + kc2 * 64 + lr4;
            #pragma unroll
            for (int g = 0; g < 17; ++g) {
                float4 w4 = *(const float4*)(wk + g * 384);
                #pragma unroll
                for (int m = 0; m < 2; ++m)
                    s[g][m] = fmaf(xv[m].x, w4.x, fmaf(xv[m].y, w4.y,
                              fmaf(xv[m].z, w4.z, fmaf(xv[m].w, w4.w, s[g][m]))));
            }
            #pragma unroll
            for (int m = 0; m < 2; ++m)
                s[17][m] = fmaf(xv[m].x, cls4.x, fmaf(xv[m].y, cls4.y,
                           fmaf(xv[m].z, cls4.z, fmaf(xv[m].w, cls4.w, s[17][m]))));
            #pragma unroll
            for (int m = 0; m < 2; ++m)
                s[18][m] = fmaf(xv[m].x, xv[m].x, fmaf(xv[m].y, xv[m].y,
                           fmaf(xv[m].z, xv[m].z, fmaf(xv[m].w, xv[m].w, s[18][m]))));
            s19 = fmaf(cls4.x, cls4.x, fmaf(cls4.y, cls4.y,
                  fmaf(cls4.z, cls4.z, fmaf(cls4.w, cls4.w, s19))));
            xv[0] = xn[0]; xv[1] = xn[1];
        }
    }

    // reduce over the 16 d-slices within each row-group
    #pragma unroll
    for (int off = 8; off >= 1; off >>= 1) {
        #pragma unroll
        for (int i = 0; i < 19; ++i)
            #pragma unroll
            for (int m = 0; m < 2; ++m)
                s[i][m] += __shfl_xor(s[i][m], off, 16);
        s19 += __shfl_xor(s19, off, 16);
    }

    __syncthreads();   // all wbuf reads done -> safe to overwrite via atile alias

    #pragma unroll
    for (int g = 0; g < 19; ++g) {
        if (lr == ((g < 16) ? g : 15)) {
            float2 v = {s[g][0], s[g][1]};
            *(float2*)&atile[g * 68 + pbase] = v;
        }
    }
    if (lr == 15) {
        float2 v = {s19, s19};
        *(float2*)&atile[19 * 68 + pbase] = v;
    }
    __syncthreads();

    if (tid < 64) {
        int p = chunk * 64 + tid;
        float v[17];
        float mx = -3.0e38f;
        #pragma unroll
        for (int g = 0; g < 17; ++g) {
            v[g] = atile[g * 68 + tid];
            mx = fmaxf(mx, v[g]);
        }
        float tot = 0.f;
        #pragma unroll
        for (int g = 0; g < 17; ++g) {
            v[g] = __expf((v[g] - mx) * INV_TEMP);
            tot += v[g];
        }
        float inv = 1.0f / tot;
        float* ap = attn + ((size_t)b * G_) * P_ + p;
        #pragma unroll
        for (int g = 0; g < 17; ++g) {
            float av = v[g] * inv;
            ap[(size_t)g * P_] = av;        // pre-occlusion attn to global
            atile[g * 68 + tid] = av;       // normalized copy for PV phase
        }
        float cd = atile[17 * 68 + tid];
        float sq = atile[18 * 68 + tid];
        float cls2 = atile[19 * 68 + tid];
        float ci = 1.0f / fmaxf(sqrtf(cls2), 1e-12f);
        sim[(size_t)b * P_ + p] = cd * ci / fmaxf(sqrtf(sq), 1e-12f);
    }
    __syncthreads();

    if (tid >= 192) return;
    // PV phase: re-read this block's own x chunk from global (L2/L3-hot).
    const float* xb = x + ((size_t)(b * NTOK) + 1 + chunk * 64) * D_ + tid * 4;
    float4 acc[G_];
    #pragma unroll
    for (int g = 0; g < G_; ++g) acc[g] = make_float4(0.f, 0.f, 0.f, 0.f);

    float4 c0 = *(const float4*)(xb + (size_t)0 * D_);
    float4 c1 = *(const float4*)(xb + (size_t)1 * D_);
    float4 c2 = *(const float4*)(xb + (size_t)2 * D_);
    float4 c3 = *(const float4*)(xb + (size_t)3 * D_);

    for (int pp = 0; pp < 64; pp += 4) {
        float4 n0 = c0, n1 = c1, n2 = c2, n3 = c3;
        if (pp + 4 < 64) {
            n0 = *(const float4*)(xb + (size_t)(pp + 4) * D_);
            n1 = *(const float4*)(xb + (size_t)(pp + 5) * D_);
            n2 = *(const float4*)(xb + (size_t)(pp + 6) * D_);
            n3 = *(const float4*)(xb + (size_t)(pp + 7) * D_);
        }
        #pragma unroll
        for (int g = 0; g < G_; ++g) {
            float4 a = *(const float4*)&atile[g * 68 + pp];   // wave-uniform broadcast
            acc[g].x = fmaf(a.x, c0.x, fmaf(a.y, c1.x, fmaf(a.z, c2.x, fmaf(a.w, c3.x, acc[g].x))));
            acc[g].y = fmaf(a.x, c0.y, fmaf(a.y, c1.y, fmaf(a.z, c2.y, fmaf(a.w, c3.y, acc[g].y))));
            acc[g].z = fmaf(a.x, c0.z, fmaf(a.y, c1.z, fmaf(a.z, c2.z, fmaf(a.w, c3.z, acc[g].z))));
            acc[g].w = fmaf(a.x, c0.w, fmaf(a.y, c1.w, fmaf(a.z, c2.w, fmaf(a.w, c3.w, acc[g].w))));
        }
        c0 = n0; c1 = n1; c2 = n2; c3 = n3;
    }

    if (use_part) {
        float* gb = gfp + ((size_t)(chunk * B_ + b) * G_) * D_ + tid * 4;
        #pragma unroll
        for (int g = 0; g < G_; ++g) *(float4*)(gb + (size_t)g * D_) = acc[g];
    } else {
        float* fb = feats + ((size_t)(b * 18) + 1) * D_ + tid * 4;
        #pragma unroll
        for (int g = 0; g < G_; ++g) {
            atomicAdd(fb + (size_t)g * D_ + 0, acc[g].x);
            atomicAdd(fb + (size_t)g * D_ + 1, acc[g].y);
            atomicAdd(fb + (size_t)g * D_ + 2, acc[g].z);
            atomicAdd(fb + (size_t)g * D_ + 3, acc[g].w);
        }
    }
}

// K24: grid (B_), block 192. Wave 0: top-k (10 smallest sims, ties -> lower
// index). All threads: cls->feats row 0 copy, then sum the 9 gfp partial
// slabs. Then snapshot pre-occlusion attn at occluded columns, stamp 1/17,
// and subtract the per-g occluded contribution sum_t a0[g,t]*x[p_t].
__global__ __launch_bounds__(192) void k24_fin(const float* __restrict__ x,
                                               const float* __restrict__ sim,
                                               const float* __restrict__ gfp,
                                               float* __restrict__ attn,
                                               float* __restrict__ feats,
                                               int use_part) {
    __shared__ int s_occ[KOCC];
    __shared__ float s_a0[KOCC][G_];
    int b = blockIdx.x, tid = threadIdx.x;

    // cls -> feats row 0 (was k0's job): 192 threads x float4 = 768 floats
    const float* clsrow = x + (size_t)b * NTOK * D_;
    float* fb0 = feats + (size_t)b * 18 * D_;
    *(float4*)(fb0 + tid * 4) = *(const float4*)(clsrow + tid * 4);

    if (tid < 64) {
        int lane = tid;
        int base = lane * 9;
        float v[9];
        #pragma unroll
        for (int j = 0; j < 9; ++j) v[j] = sim[(size_t)b * P_ + base + j];
        for (int t = 0; t < KOCC; ++t) {
            float mv = 3.0e38f;
            int mi = 1 << 30;
            #pragma unroll
            for (int j = 0; j < 9; ++j) {
                if (v[j] < mv) { mv = v[j]; mi = base + j; }
            }
            #pragma unroll
            for (int off = 1; off < 64; off <<= 1) {
                float ov = __shfl_xor(mv, off, 64);
                int oi = __shfl_xor(mi, off, 64);
                if (ov < mv || (ov == mv && oi < mi)) { mv = ov; mi = oi; }
            }
            if (lane == 0) s_occ[t] = mi;
            int loc = mi - base;
            if (loc >= 0 && loc < 9) v[loc] = 3.0e38f;
        }
    }

    // Partial sums: independent of top-k, so waves 1-2 start immediately.
    float4 acc[G_];
    float* fb = feats + ((size_t)(b * 18) + 1) * D_ + tid * 4;
    if (use_part) {
        #pragma unroll
        for (int g = 0; g < G_; ++g) acc[g] = make_float4(0.f, 0.f, 0.f, 0.f);
        for (int pc = 0; pc < NCHUNK; ++pc) {
            const float* gb = gfp + ((size_t)(pc * B_ + b) * G_) * D_ + tid * 4;
            #pragma unroll
            for (int g = 0; g < G_; ++g) {
                float4 v = *(const float4*)(gb + (size_t)g * D_);
                acc[g].x += v.x; acc[g].y += v.y; acc[g].z += v.z; acc[g].w += v.w;
            }
        }
    } else {
        #pragma unroll
        for (int g = 0; g < G_; ++g) acc[g] = *(const float4*)(fb + (size_t)g * D_);
    }
    __syncthreads();   // s_occ ready

    // Snapshot pre-occlusion attn at occluded columns, then stamp 1/17.
    // Each (t,g) entry is read and overwritten by the SAME thread -> no race.
    for (int i = tid; i < KOCC * G_; i += 192) {
        int t = i / G_, g = i - t * G_;
        size_t idx = ((size_t)b * G_ + g) * P_ + s_occ[t];
        s_a0[t][g] = attn[idx];
        attn[idx] = U17;
    }
    __syncthreads();   // s_a0 ready

    #pragma unroll
    for (int t = 0; t < KOCC; ++t) {
        float4 xo = *(const float4*)(x + ((size_t)(b * NTOK) + 1 + s_occ[t]) * D_ + tid * 4);
        #pragma unroll
        for (int g = 0; g < G_; ++g) {
            float a0 = s_a0[t][g];
            acc[g].x = fmaf(-a0, xo.x, acc[g].x);
            acc[g].y = fmaf(-a0, xo.y, acc[g].y);
            acc[g].z = fmaf(-a0, xo.z, acc[g].z);
            acc[g].w = fmaf(-a0, xo.w, acc[g].w);
        }
    }
    #pragma unroll
    for (int g = 0; g < G_; ++g) *(float4*)(fb + (size_t)g * D_) = acc[g];
}

extern "C" void kernel_launch(void* const* d_in, const int* in_sizes, int n_in,
                              void* d_out, int out_size, void* d_ws, size_t ws_size,
                              hipStream_t stream) {
    const float* x  = (const float*)d_in[0];
    const float* gw = (const float*)d_in[1];
    float* feats = (float*)d_out;                               // B*18*D
    float* attn  = (float*)d_out + (size_t)B_ * 18 * D_;        // B*17*P
    float* sim   = (float*)d_ws + OFF_SIM;
    float* gfp   = (float*)d_ws + OFF_GFP;

    int use_part = (((size_t)OFF_GFP + (size_t)NCHUNK * GFP_PART) * sizeof(float) <= ws_size);

    if (!use_part) kz_zero<<<B_, 256, 0, stream>>>(feats);
    k13_score_pv<<<dim3(NCHUNK, B_), 512, 0, stream>>>(x, gw, sim, attn, gfp, feats, use_part);
    k24_fin<<<B_, 192, 0, stream>>>(x, sim, gfp, attn, feats, use_part);
}